// Round 11
// baseline (2769.179 us; speedup 1.0000x reference)
//
#include <hip/hip_runtime.h>

typedef unsigned int u32;

#define N_TOK 65536
#define DIM 256
#define NE 4096
#define TM 128
#define TN 256
#define TK 32
#define NET (NE / TN)  // 16 et tiles

__device__ __align__(16) float g_enorm[NE];     // np-exact sum(embed^2, axis=0)
__device__ __align__(16) float g_xnorm[N_TOK];  // np-exact sum(x^2, axis=1)
__device__ float g_diffarr[64];                 // diff partial bins

__device__ __forceinline__ float sqr_rn(float v) { return __fmul_rn(v, v); }

// async 16B global->LDS (DMA). LDS dest lane-linear: f = i*512 + tid.
__device__ __forceinline__ void load16_lds(const float* __restrict__ g, float* l) {
    __builtin_amdgcn_global_load_lds(
        (const __attribute__((address_space(1))) void*)g,
        (__attribute__((address_space(3))) void*)l, 16, 0, 0);
}

// NumPy pairwise_sum for a 128-block of squares (bit-exact helper).
__device__ float np_sum128_sq(const float* __restrict__ a) {
    float r[8];
#pragma unroll
    for (int j = 0; j < 8; ++j) r[j] = sqr_rn(a[j]);
    for (int i = 8; i < 128; i += 8)
#pragma unroll
        for (int j = 0; j < 8; ++j) r[j] = __fadd_rn(r[j], sqr_rn(a[i + j]));
    return __fadd_rn(__fadd_rn(__fadd_rn(r[0], r[1]), __fadd_rn(r[2], r[3])),
                     __fadd_rn(__fadd_rn(r[4], r[5]), __fadd_rn(r[6], r[7])));
}

// ---------------- K1a: x row norms ------------------------------------------
__global__ void k_xnorm(const float* __restrict__ x) {
    const int n = blockIdx.x * 256 + threadIdx.x;
    const float* row = x + (size_t)n * DIM;
    g_xnorm[n] = __fadd_rn(np_sum128_sq(row), np_sum128_sq(row + 128));
    if (blockIdx.x == 0 && threadIdx.x < 64) g_diffarr[threadIdx.x] = 0.f;
}

// ---------------- K1b: embed col norms --------------------------------------
__global__ void k_enorm(const float* __restrict__ embed) {
    const int e = blockIdx.x * 256 + threadIdx.x;
    float s = sqr_rn(embed[e]);
    for (int d = 1; d < DIM; ++d) s = __fadd_rn(s, sqr_rn(embed[(size_t)d * NE + e]));
    g_enorm[e] = s;
}

// ---------------- K2: distance GEMM + argmin, bit-matching np float32 --------
// R11: R10's post-mortem exposed the residency law: launch_bounds 2nd arg acts
// as the waves-per-EU residency CAP on this toolchain (fits R0-R10 occupancy:
// (256,1)->11.8%, (256,2)->21%, (512,2)->23%, (1024,1)->47%). R8/R10 thus ran
// ONE 512-thr block/CU (2 waves/SIMD, grid serialized into 2 passes) -- per
// block-pass FMA-issue efficiency only 48%, stalls unhidden. This round is
// R10 byte-identical EXCEPT launch_bounds(512, 4): 4 waves/EU = 16 waves/CU =
// TWO co-resident blocks (LDS 96<160 KB, VGPR cap 128 >= our 92). Unsynced
// sibling block's FMA bursts cover each block's DMA-drain + lgkmcnt stalls.
// Inner loop (from R10): ev hoisted once per g (8 reads) + one xt per row
// (8 reads) = 16 ds_read_b128 / 256 FMA-instrs.
// Numerics: per output k=0..255 ascending single fmaf chain (kt->g->kk);
// epilogue ((xnorm - 2*mm) + enorm) each op fp32-rounded; first-min scan
// ascending in e with index tie-break -> bit-identical argmin to R0-R10.
__global__ __launch_bounds__(512, 4)
void k_argmin(const float* __restrict__ x, const float* __restrict__ embed,
              float* __restrict__ out_ind) {
    __shared__ __align__(16) float xs[TM * TK];  // 16 KB [128 rows][32 k]
    __shared__ __align__(16) float es[TK * TN];  // 32 KB [32 k][256 codes]
    const int tid = threadIdx.x;
    const int tx = tid & 31;   // 32 code-lanes; codes tx*4+{0..3} and 128+tx*4+{0..3}
    const int ty = tid >> 5;   // 0..15; token rows i*16 + ty, i=0..7
    const int n0 = blockIdx.x * TM;

    float best[8];
    int bidx[8];
#pragma unroll
    for (int i = 0; i < 8; i++) { best[i] = 3.0e38f; bidx[i] = 0; }

#pragma unroll 1
    for (int et = 0; et < NET; ++et) {
        const int e0 = et * TN;
        float acc[8][8];
#pragma unroll
        for (int i = 0; i < 8; i++)
#pragma unroll
            for (int j = 0; j < 8; j++) acc[i][j] = 0.f;

#pragma unroll 1
        for (int kt = 0; kt < DIM / TK; ++kt) {
            const int k0 = kt * TK;
            __syncthreads();  // all waves done reading previous tile
            // xs stage: 1024 f4 slots; f -> row r=f>>3, k-group c=f&7
#pragma unroll
            for (int i_ = 0; i_ < 2; ++i_) {
                const int f_ = i_ * 512 + tid;
                const int r_ = f_ >> 3, c_ = f_ & 7;
                load16_lds(x + (size_t)(n0 + r_) * DIM + k0 + c_ * 4, xs + f_ * 4);
            }
            // es stage: 2048 f4 slots; f -> k row r=f>>6, code-group c=f&63
#pragma unroll
            for (int i_ = 0; i_ < 4; ++i_) {
                const int f_ = i_ * 512 + tid;
                const int r_ = f_ >> 6, c_ = f_ & 63;
                load16_lds(embed + (size_t)(k0 + r_) * NE + e0 + c_ * 4, es + f_ * 4);
            }
            __syncthreads();  // implicit vmcnt(0) drain -> DMA data visible

#pragma unroll 1
            for (int g = 0; g < 8; ++g) {
                // ev once per g: 8 b128 reads, 32 regs live across the row loop
                float4 ea[4], eb[4];
#pragma unroll
                for (int kk = 0; kk < 4; ++kk) {
                    const int kb = (g * 4 + kk) * TN;
                    ea[kk] = *(const float4*)&es[kb + tx * 4];
                    eb[kk] = *(const float4*)&es[kb + 128 + tx * 4];
                }
                // one row at a time: 1 xt read per 32 FMAs
#pragma unroll
                for (int i = 0; i < 8; ++i) {
                    const float4 xt = *(const float4*)&xs[(i * 16 + ty) * TK + g * 4];
#pragma unroll
                    for (int kk = 0; kk < 4; ++kk) {  // k ascending: one FMA chain
                        const float xk = kk == 0 ? xt.x
                                       : kk == 1 ? xt.y
                                       : kk == 2 ? xt.z : xt.w;
                        acc[i][0] = fmaf(xk, ea[kk].x, acc[i][0]);
                        acc[i][1] = fmaf(xk, ea[kk].y, acc[i][1]);
                        acc[i][2] = fmaf(xk, ea[kk].z, acc[i][2]);
                        acc[i][3] = fmaf(xk, ea[kk].w, acc[i][3]);
                        acc[i][4] = fmaf(xk, eb[kk].x, acc[i][4]);
                        acc[i][5] = fmaf(xk, eb[kk].y, acc[i][5]);
                        acc[i][6] = fmaf(xk, eb[kk].z, acc[i][6]);
                        acc[i][7] = fmaf(xk, eb[kk].w, acc[i][7]);
                    }
                }
            }
        }

        // epilogue: np ((xnorm - 2*mm) + enorm), each op fp32-rounded;
        // within-thread scan ascending in e: j<4 -> tx*4+j, j>=4 -> 128+tx*4+(j-4)
        const float4 ena = *(const float4*)&g_enorm[e0 + tx * 4];
        const float4 enb = *(const float4*)&g_enorm[e0 + 128 + tx * 4];
        const float enj[8] = {ena.x, ena.y, ena.z, ena.w, enb.x, enb.y, enb.z, enb.w};
#pragma unroll
        for (int i = 0; i < 8; i++) {
            const float xnv = g_xnorm[n0 + i * 16 + ty];  // reload: saves 8 regs
#pragma unroll
            for (int j = 0; j < 8; j++) {
                float v = __fadd_rn(__fsub_rn(xnv, __fmul_rn(2.0f, acc[i][j])), enj[j]);
                int e = e0 + (j >> 2) * 128 + tx * 4 + (j & 3);
                if (v < best[i]) { best[i] = v; bidx[i] = e; }
            }
        }
    }
    // reduce across the 32 tx lanes per token row (masks 1..16 stay within each
    // wave half = one ty); ties -> smaller index (np first-min)
#pragma unroll
    for (int i = 0; i < 8; i++) {
        float b = best[i];
        int bi = bidx[i];
#pragma unroll
        for (int m = 1; m < 32; m <<= 1) {
            float ob = __shfl_xor(b, m, 64);
            int oi = __shfl_xor(bi, m, 64);
            if (ob < b || (ob == b && oi < bi)) { b = ob; bi = oi; }
        }
        if (tx == 0) out_ind[n0 + i * 16 + ty] = (float)bi;
    }
}

// ---------------- K3: gather quantize (fp32) + diff partials -----------------
__global__ void k_gather(const float* __restrict__ x, const float* __restrict__ embed,
                         const float* __restrict__ out_ind, float* __restrict__ outq) {
    const int n = blockIdx.x;
    const int d = threadIdx.x;
    int e = (int)out_ind[n];
    e = e < 0 ? 0 : (e > NE - 1 ? NE - 1 : e);  // OOB-proof
    const float v = embed[(size_t)d * NE + e];
    outq[(size_t)n * DIM + d] = v;
    float sq = v - x[(size_t)n * DIM + d];
    sq *= sq;
#pragma unroll
    for (int m = 1; m < 64; m <<= 1) sq += __shfl_xor(sq, m, 64);
    __shared__ float wsum[4];
    if ((d & 63) == 0) wsum[d >> 6] = sq;
    __syncthreads();
    if (d == 0) atomicAdd(&g_diffarr[n & 63], wsum[0] + wsum[1] + wsum[2] + wsum[3]);
}

// ---------------- K4: publish diff -------------------------------------------
__global__ void k_finish(float* __restrict__ out_diff) {
    float t = 0.f;
    for (int w = 0; w < 64; ++w) t += g_diffarr[w];
    if (threadIdx.x == 0) *out_diff = t * (1.0f / 16777216.0f);
}

extern "C" void kernel_launch(void* const* d_in, const int* in_sizes, int n_in,
                              void* d_out, int out_size, void* d_ws, size_t ws_size,
                              hipStream_t stream) {
    const float* x = (const float*)d_in[0];      // [65536, 256]
    const float* embed = (const float*)d_in[1];  // [256, 4096]
    float* outq = (float*)d_out;                 // quantize
    float* out_diff = outq + 16777216;           // diff scalar
    float* out_ind = outq + 16777217;            // embed_ind (float-coded)

    hipLaunchKernelGGL(k_xnorm, dim3(N_TOK / 256), dim3(256), 0, stream, x);
    hipLaunchKernelGGL(k_enorm, dim3(NE / 256), dim3(256), 0, stream, embed);
    hipLaunchKernelGGL(k_argmin, dim3(N_TOK / TM), dim3(512), 0, stream, x, embed, out_ind);
    hipLaunchKernelGGL(k_gather, dim3(N_TOK), dim3(256), 0, stream, x, embed, out_ind, outq);
    hipLaunchKernelGGL(k_finish, dim3(1), dim3(64), 0, stream, out_diff);
}

// Round 12
// 1994.977 us; speedup vs baseline: 1.3881x; 1.3881x over previous
//
#include <hip/hip_runtime.h>

typedef unsigned int u32;

#define N_TOK 65536
#define DIM 256
#define NE 4096
#define TM 128
#define TN 256
#define TK 32
#define NET (NE / TN)   // 16 et tiles
#define NT (NET * 8)    // 128 pipeline steps (8 kt per et)

__device__ __align__(16) float g_enorm[NE];     // np-exact sum(embed^2, axis=0)
__device__ __align__(16) float g_xnorm[N_TOK];  // np-exact sum(x^2, axis=1)
__device__ float g_diffarr[64];                 // diff partial bins

__device__ __forceinline__ float sqr_rn(float v) { return __fmul_rn(v, v); }

// async 16B global->LDS (DMA). LDS dest lane-linear: f = i*512 + tid.
__device__ __forceinline__ void load16_lds(const float* __restrict__ g, float* l) {
    __builtin_amdgcn_global_load_lds(
        (const __attribute__((address_space(1))) void*)g,
        (__attribute__((address_space(3))) void*)l, 16, 0, 0);
}

// NumPy pairwise_sum for a 128-block of squares (bit-exact helper).
__device__ float np_sum128_sq(const float* __restrict__ a) {
    float r[8];
#pragma unroll
    for (int j = 0; j < 8; ++j) r[j] = sqr_rn(a[j]);
    for (int i = 8; i < 128; i += 8)
#pragma unroll
        for (int j = 0; j < 8; ++j) r[j] = __fadd_rn(r[j], sqr_rn(a[i + j]));
    return __fadd_rn(__fadd_rn(__fadd_rn(r[0], r[1]), __fadd_rn(r[2], r[3])),
                     __fadd_rn(__fadd_rn(r[4], r[5]), __fadd_rn(r[6], r[7])));
}

// ---------------- K1a: x row norms ------------------------------------------
__global__ void k_xnorm(const float* __restrict__ x) {
    const int n = blockIdx.x * 256 + threadIdx.x;
    const float* row = x + (size_t)n * DIM;
    g_xnorm[n] = __fadd_rn(np_sum128_sq(row), np_sum128_sq(row + 128));
    if (blockIdx.x == 0 && threadIdx.x < 64) g_diffarr[threadIdx.x] = 0.f;
}

// ---------------- K1b: embed col norms --------------------------------------
__global__ void k_enorm(const float* __restrict__ embed) {
    const int e = blockIdx.x * 256 + threadIdx.x;
    float s = sqr_rn(embed[e]);
    for (int d = 1; d < DIM; ++d) s = __fadd_rn(s, sqr_rn(embed[(size_t)d * NE + e]));
    g_enorm[e] = s;
}

// ---------------- K2: distance GEMM + argmin, bit-matching np float32 --------
// R12: R11 refined the law: launch_bounds arg2 scales BOTH residency and the
// VGPR cap ((512,2)->128, (512,4)->64); 16 waves/CU is unreachable without
// spilling the 64-reg accumulator -> (512,2)/VGPR<=128 is the residency
// optimum. R8/R10's residue: 7.25us/kt vs 3.4us FMA issue -- the single-buffer
// per-kt [barrier -> DMA issue -> barrier w/ vmcnt(0) drain] puts a full HBM
// latency on every wave's critical path each kt. Fix (R4's structure, now at
// 2 waves/SIMD): double-buffered xs/es (96 KB), ONE barrier per step, DMA for
// step t+1 issued right after the barrier of step t -> by the time step t+1's
// barrier drains vmcnt, the loads are a full ~4us compute phase old => free.
// Inner loop unchanged from R10 (ev hoisted per g, 16 ds_read_b128/256 FMAs).
// Numerics: per output k=0..255 ascending single fmaf chain (et->kt->g->kk);
// epilogue ((xnorm - 2*mm) + enorm) each op fp32-rounded; first-min scan
// ascending in e with index tie-break -> bit-identical argmin to R0-R11.
__global__ __launch_bounds__(512, 2)
void k_argmin(const float* __restrict__ x, const float* __restrict__ embed,
              float* __restrict__ out_ind) {
    __shared__ __align__(16) float xs0[TM * TK];  // 16 KB [128 rows][32 k]
    __shared__ __align__(16) float xs1[TM * TK];
    __shared__ __align__(16) float es0[TK * TN];  // 32 KB [32 k][256 codes]
    __shared__ __align__(16) float es1[TK * TN];
    const int tid = threadIdx.x;
    const int tx = tid & 31;   // 32 code-lanes; codes tx*4+{0..3} and 128+tx*4+{0..3}
    const int ty = tid >> 5;   // 0..15; token rows i*16 + ty, i=0..7
    const int n0 = blockIdx.x * TM;

    // stage step t (et = t>>3, kt = t&7) into (xsd, esd)
    auto stage = [&](float* xsd, float* esd, int t) {
        const int k0 = (t & 7) * TK;
        const int e0_ = (t >> 3) * TN;
#pragma unroll
        for (int i_ = 0; i_ < 2; ++i_) {  // xs: 1024 f4 slots
            const int f_ = i_ * 512 + tid;
            const int r_ = f_ >> 3, c_ = f_ & 7;
            load16_lds(x + (size_t)(n0 + r_) * DIM + k0 + c_ * 4, xsd + f_ * 4);
        }
#pragma unroll
        for (int i_ = 0; i_ < 4; ++i_) {  // es: 2048 f4 slots
            const int f_ = i_ * 512 + tid;
            const int r_ = f_ >> 6, c_ = f_ & 63;
            load16_lds(embed + (size_t)(k0 + r_) * NE + e0_ + c_ * 4, esd + f_ * 4);
        }
    };

    stage(xs0, es0, 0);  // prologue: step 0 -> buffer 0

    float best[8];
    int bidx[8];
#pragma unroll
    for (int i = 0; i < 8; i++) { best[i] = 3.0e38f; bidx[i] = 0; }

    float acc[8][8];
#pragma unroll 1
    for (int t = 0; t < NT; ++t) {
        const int kt = t & 7;
        if (kt == 0) {
#pragma unroll
            for (int i = 0; i < 8; i++)
#pragma unroll
                for (int j = 0; j < 8; j++) acc[i][j] = 0.f;
        }
        __syncthreads();  // drains stage(t) DMA (issued one full compute phase
                          // ago -> free); syncs readers of the buffer we'll
                          // overwrite next (last read in step t-1)
        if (t + 1 < NT) {
            if (t & 1) stage(xs0, es0, t + 1);
            else       stage(xs1, es1, t + 1);
        }
        const float* __restrict__ xsr = (t & 1) ? xs1 : xs0;
        const float* __restrict__ esr = (t & 1) ? es1 : es0;

#pragma unroll 1
        for (int g = 0; g < 8; ++g) {
            // ev once per g: 8 b128 reads, 32 regs live across the row loop
            float4 ea[4], eb[4];
#pragma unroll
            for (int kk = 0; kk < 4; ++kk) {
                const int kb = (g * 4 + kk) * TN;
                ea[kk] = *(const float4*)&esr[kb + tx * 4];
                eb[kk] = *(const float4*)&esr[kb + 128 + tx * 4];
            }
            // one row at a time: 1 xt read per 32 FMAs
#pragma unroll
            for (int i = 0; i < 8; ++i) {
                const float4 xt = *(const float4*)&xsr[(i * 16 + ty) * TK + g * 4];
#pragma unroll
                for (int kk = 0; kk < 4; ++kk) {  // k ascending: one FMA chain
                    const float xk = kk == 0 ? xt.x
                                   : kk == 1 ? xt.y
                                   : kk == 2 ? xt.z : xt.w;
                    acc[i][0] = fmaf(xk, ea[kk].x, acc[i][0]);
                    acc[i][1] = fmaf(xk, ea[kk].y, acc[i][1]);
                    acc[i][2] = fmaf(xk, ea[kk].z, acc[i][2]);
                    acc[i][3] = fmaf(xk, ea[kk].w, acc[i][3]);
                    acc[i][4] = fmaf(xk, eb[kk].x, acc[i][4]);
                    acc[i][5] = fmaf(xk, eb[kk].y, acc[i][5]);
                    acc[i][6] = fmaf(xk, eb[kk].z, acc[i][6]);
                    acc[i][7] = fmaf(xk, eb[kk].w, acc[i][7]);
                }
            }
        }

        if (kt == 7) {
            // epilogue for et = t>>3: np ((xnorm - 2*mm) + enorm), fp32-rounded;
            // within-thread scan ascending in e
            const int e0 = (t >> 3) * TN;
            const float4 ena = *(const float4*)&g_enorm[e0 + tx * 4];
            const float4 enb = *(const float4*)&g_enorm[e0 + 128 + tx * 4];
            const float enj[8] = {ena.x, ena.y, ena.z, ena.w,
                                  enb.x, enb.y, enb.z, enb.w};
#pragma unroll
            for (int i = 0; i < 8; i++) {
                const float xnv = g_xnorm[n0 + i * 16 + ty];
#pragma unroll
                for (int j = 0; j < 8; j++) {
                    float v = __fadd_rn(__fsub_rn(xnv, __fmul_rn(2.0f, acc[i][j])), enj[j]);
                    int e = e0 + (j >> 2) * 128 + tx * 4 + (j & 3);
                    if (v < best[i]) { best[i] = v; bidx[i] = e; }
                }
            }
        }
    }
    // reduce across the 32 tx lanes per token row (masks 1..16 stay within each
    // wave half = one ty); ties -> smaller index (np first-min)
#pragma unroll
    for (int i = 0; i < 8; i++) {
        float b = best[i];
        int bi = bidx[i];
#pragma unroll
        for (int m = 1; m < 32; m <<= 1) {
            float ob = __shfl_xor(b, m, 64);
            int oi = __shfl_xor(bi, m, 64);
            if (ob < b || (ob == b && oi < bi)) { b = ob; bi = oi; }
        }
        if (tx == 0) out_ind[n0 + i * 16 + ty] = (float)bi;
    }
}

// ---------------- K3: gather quantize (fp32) + diff partials -----------------
__global__ void k_gather(const float* __restrict__ x, const float* __restrict__ embed,
                         const float* __restrict__ out_ind, float* __restrict__ outq) {
    const int n = blockIdx.x;
    const int d = threadIdx.x;
    int e = (int)out_ind[n];
    e = e < 0 ? 0 : (e > NE - 1 ? NE - 1 : e);  // OOB-proof
    const float v = embed[(size_t)d * NE + e];
    outq[(size_t)n * DIM + d] = v;
    float sq = v - x[(size_t)n * DIM + d];
    sq *= sq;
#pragma unroll
    for (int m = 1; m < 64; m <<= 1) sq += __shfl_xor(sq, m, 64);
    __shared__ float wsum[4];
    if ((d & 63) == 0) wsum[d >> 6] = sq;
    __syncthreads();
    if (d == 0) atomicAdd(&g_diffarr[n & 63], wsum[0] + wsum[1] + wsum[2] + wsum[3]);
}

// ---------------- K4: publish diff -------------------------------------------
__global__ void k_finish(float* __restrict__ out_diff) {
    float t = 0.f;
    for (int w = 0; w < 64; ++w) t += g_diffarr[w];
    if (threadIdx.x == 0) *out_diff = t * (1.0f / 16777216.0f);
}

extern "C" void kernel_launch(void* const* d_in, const int* in_sizes, int n_in,
                              void* d_out, int out_size, void* d_ws, size_t ws_size,
                              hipStream_t stream) {
    const float* x = (const float*)d_in[0];      // [65536, 256]
    const float* embed = (const float*)d_in[1];  // [256, 4096]
    float* outq = (float*)d_out;                 // quantize
    float* out_diff = outq + 16777216;           // diff scalar
    float* out_ind = outq + 16777217;            // embed_ind (float-coded)

    hipLaunchKernelGGL(k_xnorm, dim3(N_TOK / 256), dim3(256), 0, stream, x);
    hipLaunchKernelGGL(k_enorm, dim3(NE / 256), dim3(256), 0, stream, embed);
    hipLaunchKernelGGL(k_argmin, dim3(N_TOK / TM), dim3(512), 0, stream, x, embed, out_ind);
    hipLaunchKernelGGL(k_gather, dim3(N_TOK), dim3(256), 0, stream, x, embed, out_ind, outq);
    hipLaunchKernelGGL(k_finish, dim3(1), dim3(64), 0, stream, out_diff);
}

// Round 13
// 1988.344 us; speedup vs baseline: 1.3927x; 1.0033x over previous
//
#include <hip/hip_runtime.h>

typedef unsigned int u32;

#define N_TOK 65536
#define DIM 256
#define NE 4096
#define TM 128
#define TN 256
#define TK 32
#define NET (NE / TN)   // 16 et tiles
#define NT (NET * 8)    // 128 pipeline steps (8 kt per et)

__device__ __align__(16) float g_enorm[NE];     // np-exact sum(embed^2, axis=0)
__device__ __align__(16) float g_xnorm[N_TOK];  // np-exact sum(x^2, axis=1)
__device__ float g_diffarr[64];                 // diff partial bins

__device__ __forceinline__ float sqr_rn(float v) { return __fmul_rn(v, v); }

// async 16B global->LDS (DMA). LDS dest lane-linear: f = i*512 + tid.
__device__ __forceinline__ void load16_lds(const float* __restrict__ g, float* l) {
    __builtin_amdgcn_global_load_lds(
        (const __attribute__((address_space(1))) void*)g,
        (__attribute__((address_space(3))) void*)l, 16, 0, 0);
}

// NumPy pairwise_sum for a 128-block of squares (bit-exact helper).
__device__ float np_sum128_sq(const float* __restrict__ a) {
    float r[8];
#pragma unroll
    for (int j = 0; j < 8; ++j) r[j] = sqr_rn(a[j]);
    for (int i = 8; i < 128; i += 8)
#pragma unroll
        for (int j = 0; j < 8; ++j) r[j] = __fadd_rn(r[j], sqr_rn(a[i + j]));
    return __fadd_rn(__fadd_rn(__fadd_rn(r[0], r[1]), __fadd_rn(r[2], r[3])),
                     __fadd_rn(__fadd_rn(r[4], r[5]), __fadd_rn(r[6], r[7])));
}

// ---------------- K1a: x row norms ------------------------------------------
__global__ void k_xnorm(const float* __restrict__ x) {
    const int n = blockIdx.x * 256 + threadIdx.x;
    const float* row = x + (size_t)n * DIM;
    g_xnorm[n] = __fadd_rn(np_sum128_sq(row), np_sum128_sq(row + 128));
    if (blockIdx.x == 0 && threadIdx.x < 64) g_diffarr[threadIdx.x] = 0.f;
}

// ---------------- K1b: embed col norms --------------------------------------
__global__ void k_enorm(const float* __restrict__ embed) {
    const int e = blockIdx.x * 256 + threadIdx.x;
    float s = sqr_rn(embed[e]);
    for (int d = 1; d < DIM; ++d) s = __fadd_rn(s, sqr_rn(embed[(size_t)d * NE + e]));
    g_enorm[e] = s;
}

// ---------------- K2: distance GEMM + argmin, bit-matching np float32 --------
// R13: R12 closed the barrier-drain stall (dbuf, one barrier/step). Residual:
// 6.85 us/step vs 3.41 us FMA issue -- per-row xt ds_read issued right before
// its 32 FMAs (120cyc latency vs 64cyc cover = ~56cyc exposed x 8 rows/g).
// Fix: 2-slot xt prefetch ring -- row i+1's read issued BEFORE row i's FMAs
// (static indices after full unroll, rule #20), so each read has a full
// 64-cycle FMA block between issue and first use; the g-entry ev wait is the
// only residual and the sibling wave covers it. +4 VGPR (~104 < 128 cap).
// Everything else identical to R12: (512,2), TM128xTN256, dbuf 96 KB LDS,
// DMA stage for t+1 issued right after step-t barrier, ev hoisted per g
// (16 ds_read_b128 / 256 FMA-instrs).
// Numerics: per output k=0..255 ascending single fmaf chain (et->kt->g->kk);
// epilogue ((xnorm - 2*mm) + enorm) each op fp32-rounded; first-min scan
// ascending in e with index tie-break -> bit-identical argmin to R0-R12.
__global__ __launch_bounds__(512, 2)
void k_argmin(const float* __restrict__ x, const float* __restrict__ embed,
              float* __restrict__ out_ind) {
    __shared__ __align__(16) float xs0[TM * TK];  // 16 KB [128 rows][32 k]
    __shared__ __align__(16) float xs1[TM * TK];
    __shared__ __align__(16) float es0[TK * TN];  // 32 KB [32 k][256 codes]
    __shared__ __align__(16) float es1[TK * TN];
    const int tid = threadIdx.x;
    const int tx = tid & 31;   // 32 code-lanes; codes tx*4+{0..3} and 128+tx*4+{0..3}
    const int ty = tid >> 5;   // 0..15; token rows i*16 + ty, i=0..7
    const int n0 = blockIdx.x * TM;

    // stage step t (et = t>>3, kt = t&7) into (xsd, esd)
    auto stage = [&](float* xsd, float* esd, int t) {
        const int k0 = (t & 7) * TK;
        const int e0_ = (t >> 3) * TN;
#pragma unroll
        for (int i_ = 0; i_ < 2; ++i_) {  // xs: 1024 f4 slots
            const int f_ = i_ * 512 + tid;
            const int r_ = f_ >> 3, c_ = f_ & 7;
            load16_lds(x + (size_t)(n0 + r_) * DIM + k0 + c_ * 4, xsd + f_ * 4);
        }
#pragma unroll
        for (int i_ = 0; i_ < 4; ++i_) {  // es: 2048 f4 slots
            const int f_ = i_ * 512 + tid;
            const int r_ = f_ >> 6, c_ = f_ & 63;
            load16_lds(embed + (size_t)(k0 + r_) * NE + e0_ + c_ * 4, esd + f_ * 4);
        }
    };

    stage(xs0, es0, 0);  // prologue: step 0 -> buffer 0

    float best[8];
    int bidx[8];
#pragma unroll
    for (int i = 0; i < 8; i++) { best[i] = 3.0e38f; bidx[i] = 0; }

    float acc[8][8];
#pragma unroll 1
    for (int t = 0; t < NT; ++t) {
        const int kt = t & 7;
        if (kt == 0) {
#pragma unroll
            for (int i = 0; i < 8; i++)
#pragma unroll
                for (int j = 0; j < 8; j++) acc[i][j] = 0.f;
        }
        __syncthreads();  // drains stage(t) DMA (issued one full compute phase
                          // ago -> free); syncs readers of the buffer we'll
                          // overwrite next (last read in step t-1)
        if (t + 1 < NT) {
            if (t & 1) stage(xs0, es0, t + 1);
            else       stage(xs1, es1, t + 1);
        }
        const float* __restrict__ xsr = (t & 1) ? xs1 : xs0;
        const float* __restrict__ esr = (t & 1) ? es1 : es0;

#pragma unroll 1
        for (int g = 0; g < 8; ++g) {
            // row-0 xt first (latency hides under ev service), then ev once per g
            float4 xtb[2];
            xtb[0] = *(const float4*)&xsr[(ty)*TK + g * 4];
            float4 ea[4], eb[4];
#pragma unroll
            for (int kk = 0; kk < 4; ++kk) {
                const int kb = (g * 4 + kk) * TN;
                ea[kk] = *(const float4*)&esr[kb + tx * 4];
                eb[kk] = *(const float4*)&esr[kb + 128 + tx * 4];
            }
            // 2-slot prefetch ring: issue row i+1's read before row i's FMAs
#pragma unroll
            for (int i = 0; i < 8; ++i) {
                if (i < 7)
                    xtb[(i + 1) & 1] =
                        *(const float4*)&xsr[((i + 1) * 16 + ty) * TK + g * 4];
                const float4 xt = xtb[i & 1];
#pragma unroll
                for (int kk = 0; kk < 4; ++kk) {  // k ascending: one FMA chain
                    const float xk = kk == 0 ? xt.x
                                   : kk == 1 ? xt.y
                                   : kk == 2 ? xt.z : xt.w;
                    acc[i][0] = fmaf(xk, ea[kk].x, acc[i][0]);
                    acc[i][1] = fmaf(xk, ea[kk].y, acc[i][1]);
                    acc[i][2] = fmaf(xk, ea[kk].z, acc[i][2]);
                    acc[i][3] = fmaf(xk, ea[kk].w, acc[i][3]);
                    acc[i][4] = fmaf(xk, eb[kk].x, acc[i][4]);
                    acc[i][5] = fmaf(xk, eb[kk].y, acc[i][5]);
                    acc[i][6] = fmaf(xk, eb[kk].z, acc[i][6]);
                    acc[i][7] = fmaf(xk, eb[kk].w, acc[i][7]);
                }
            }
        }

        if (kt == 7) {
            // epilogue for et = t>>3: np ((xnorm - 2*mm) + enorm), fp32-rounded;
            // within-thread scan ascending in e
            const int e0 = (t >> 3) * TN;
            const float4 ena = *(const float4*)&g_enorm[e0 + tx * 4];
            const float4 enb = *(const float4*)&g_enorm[e0 + 128 + tx * 4];
            const float enj[8] = {ena.x, ena.y, ena.z, ena.w,
                                  enb.x, enb.y, enb.z, enb.w};
#pragma unroll
            for (int i = 0; i < 8; i++) {
                const float xnv = g_xnorm[n0 + i * 16 + ty];
#pragma unroll
                for (int j = 0; j < 8; j++) {
                    float v = __fadd_rn(__fsub_rn(xnv, __fmul_rn(2.0f, acc[i][j])), enj[j]);
                    int e = e0 + (j >> 2) * 128 + tx * 4 + (j & 3);
                    if (v < best[i]) { best[i] = v; bidx[i] = e; }
                }
            }
        }
    }
    // reduce across the 32 tx lanes per token row (masks 1..16 stay within each
    // wave half = one ty); ties -> smaller index (np first-min)
#pragma unroll
    for (int i = 0; i < 8; i++) {
        float b = best[i];
        int bi = bidx[i];
#pragma unroll
        for (int m = 1; m < 32; m <<= 1) {
            float ob = __shfl_xor(b, m, 64);
            int oi = __shfl_xor(bi, m, 64);
            if (ob < b || (ob == b && oi < bi)) { b = ob; bi = oi; }
        }
        if (tx == 0) out_ind[n0 + i * 16 + ty] = (float)bi;
    }
}

// ---------------- K3: gather quantize (fp32) + diff partials -----------------
__global__ void k_gather(const float* __restrict__ x, const float* __restrict__ embed,
                         const float* __restrict__ out_ind, float* __restrict__ outq) {
    const int n = blockIdx.x;
    const int d = threadIdx.x;
    int e = (int)out_ind[n];
    e = e < 0 ? 0 : (e > NE - 1 ? NE - 1 : e);  // OOB-proof
    const float v = embed[(size_t)d * NE + e];
    outq[(size_t)n * DIM + d] = v;
    float sq = v - x[(size_t)n * DIM + d];
    sq *= sq;
#pragma unroll
    for (int m = 1; m < 64; m <<= 1) sq += __shfl_xor(sq, m, 64);
    __shared__ float wsum[4];
    if ((d & 63) == 0) wsum[d >> 6] = sq;
    __syncthreads();
    if (d == 0) atomicAdd(&g_diffarr[n & 63], wsum[0] + wsum[1] + wsum[2] + wsum[3]);
}

// ---------------- K4: publish diff -------------------------------------------
__global__ void k_finish(float* __restrict__ out_diff) {
    float t = 0.f;
    for (int w = 0; w < 64; ++w) t += g_diffarr[w];
    if (threadIdx.x == 0) *out_diff = t * (1.0f / 16777216.0f);
}

extern "C" void kernel_launch(void* const* d_in, const int* in_sizes, int n_in,
                              void* d_out, int out_size, void* d_ws, size_t ws_size,
                              hipStream_t stream) {
    const float* x = (const float*)d_in[0];      // [65536, 256]
    const float* embed = (const float*)d_in[1];  // [256, 4096]
    float* outq = (float*)d_out;                 // quantize
    float* out_diff = outq + 16777216;           // diff scalar
    float* out_ind = outq + 16777217;            // embed_ind (float-coded)

    hipLaunchKernelGGL(k_xnorm, dim3(N_TOK / 256), dim3(256), 0, stream, x);
    hipLaunchKernelGGL(k_enorm, dim3(NE / 256), dim3(256), 0, stream, embed);
    hipLaunchKernelGGL(k_argmin, dim3(N_TOK / TM), dim3(512), 0, stream, x, embed, out_ind);
    hipLaunchKernelGGL(k_gather, dim3(N_TOK), dim3(256), 0, stream, x, embed, out_ind, outq);
    hipLaunchKernelGGL(k_finish, dim3(1), dim3(64), 0, stream, out_diff);
}